// Round 12
// baseline (247.949 us; speedup 1.0000x reference)
//
#include <hip/hip_runtime.h>
#include <cfloat>
#include <math.h>
#include <stdint.h>

// Match XLA-CPU f32 arithmetic exactly: no implicit contraction anywhere;
// FMA only where written explicitly (Eigen-gemm-style cross product).
// v_pk_fma_f32 / v_pk_mul_f32 / v_pk_add_f32 are IEEE-identical per
// component to their scalar forms, so packing does not change results.
#pragma clang fp contract(off)

typedef float v2f __attribute__((ext_vector_type(2)));

#define RPW 16       // receivers per block (quarter of B=64)
#define NQ  256      // tile phases; grid = 4*NQ = 1024. PROVEN geometry (r3/
                     // r8/r10): each CU hosts the 4 receiver-quarters at the
                     // SAME phase -> one shared tile stream, FETCH ~30MB.
                     // r5/r6/r11: every larger-grid variant broke locality.
#define PPL 8        // points per lane per tile iteration
#define TILESZ (256 * PPL)   // 2048 points per tile

__device__ __forceinline__ uint32_t monotone_key(float f) {
    uint32_t u = __float_as_uint(f);
    return (u & 0x80000000u) ? ~u : (u | 0x80000000u);
}

// force a wave-uniform float into an SGPR
__device__ __forceinline__ float rfl_f(float x) {
    return __uint_as_float((uint32_t)__builtin_amdgcn_readfirstlane((int)__float_as_uint(x)));
}

__device__ __forceinline__ unsigned long long shfl_xor_u64(unsigned long long v, int m) {
    uint32_t lo = (uint32_t)v, hi = (uint32_t)(v >> 32);
    lo = (uint32_t)__shfl_xor((int)lo, m, 64);
    hi = (uint32_t)__shfl_xor((int)hi, m, 64);
    return ((unsigned long long)hi << 32) | lo;
}

__device__ __forceinline__ v2f sp(float s) { return (v2f){s, s}; }
__device__ __forceinline__ v2f pkfma(v2f a, v2f b, v2f c) {
    return __builtin_elementwise_fma(a, b, c);   // -> v_pk_fma_f32
}

// lane = 8-point group; 16 receivers in SGPRs; packed-f32 inner loop.
// DISTANCE-2 REGISTER PREFETCH: two 6xfloat4 buffers (A/B), 2x-unrolled
// loop; tile t's loads are issued two eval-bodies (~2000+ cyc) before use,
// fully covering HBM/L3 latency that distance-1 (r10, ~30us stall) missed.
// Exactness: per-component pk ops == scalar ops; rsq hoist is bit-exact
// (round() monotone => min_j round(v_j+r) == round(min_j v_j + r)); group
// update strict-< in d2-space; packed u64 (mono(d2)<<32 | group) atomicMin
// resolves ties toward the lowest group id => reference first-occurrence
// argmin lies in the winning group; finalize re-evaluates it bit-identically.
// launch_bounds(256,4): cap 128 VGPRs — do NOT squeeze the allocator (r4:
// (256,8) forced VGPR=32 and spilled best[]/grp[] to scratch, +600MB HBM).
__global__ void __launch_bounds__(256, 4) fused_kernel(
        const float* __restrict__ mesh, const float* __restrict__ recv,
        float* __restrict__ out, unsigned long long* __restrict__ ws,
        int L, int B, int ntiles) {
    __shared__ unsigned long long wmin[4][RPW];

    const int tid  = threadIdx.x;
    const int lane = tid & 63;
    const int wave = tid >> 6;
    const int rq   = blockIdx.x >> 8;      // receiver quarter 0..3
    const int q0   = blockIdx.x & 255;     // tile phase (shared by CU-mates)

    // ---- receiver set into SGPRs (once) ----
    float rx[RPW], ry[RPW], rz[RPW], rsq[RPW];
#pragma unroll
    for (int c = 0; c < RPW; ++c) {
        const int r = rq * RPW + c;
        float x = 0.f, y = 0.f, z = 0.f;
        if (r < B) {                       // uniform branch
            x = recv[r * 3 + 0];
            y = recv[r * 3 + 1];
            z = recv[r * 3 + 2];
        }
        rx[c]  = rfl_f(x);
        ry[c]  = rfl_f(y);
        rz[c]  = rfl_f(z);
        rsq[c] = rfl_f((x * x + y * y) + z * z);   // no FMA (pragma)
    }

    float    best[RPW];
    uint32_t grp[RPW];
#pragma unroll
    for (int c = 0; c < RPW; ++c) { best[c] = FLT_MAX; grp[c] = 0; }

    const bool writer = (rq == 0);         // dedicated writer quarter (proven)
    const int  laneOff = (wave << 9) + (lane << 3);

    // ---- distance-2 prologue: load tiles q0 and q0+NQ ----
    float4 A0, A1, A2, A3, A4, A5;         // slot A buffer
    float4 B0, B1, B2, B3, B4, B5;         // slot B buffer
    {
        const int pA = q0 * TILESZ + laneOff;
        if (q0 < ntiles && pA + PPL <= L) {
            const float4* __restrict__ m4 = (const float4*)(mesh + (size_t)pA * 3);
            A0 = m4[0]; A1 = m4[1]; A2 = m4[2]; A3 = m4[3]; A4 = m4[4]; A5 = m4[5];
        }
        const int tB = q0 + NQ;
        const int pB = tB * TILESZ + laneOff;
        if (tB < ntiles && pB + PPL <= L) {
            const float4* __restrict__ m4 = (const float4*)(mesh + (size_t)pB * 3);
            B0 = m4[0]; B1 = m4[1]; B2 = m4[2]; B3 = m4[3]; B4 = m4[4]; B5 = m4[5];
        }
    }

    // per-tile body: unpack slot buffer -> prefetch t+2NQ into it -> eval.
#define TILE_BODY(N0, N1, N2, N3, N4, N5, TCUR)                                \
    {                                                                          \
        const int p0_ = (TCUR) * TILESZ + laneOff;                             \
        const bool full_ = (p0_ + PPL <= L);                                   \
        v2f x2[4], y2[4], z2[4], ms2[4];                                       \
        if (full_) {   /* unpack point-pairs (2j,2j+1); frees buffer regs */   \
            x2[0]=(v2f){N0.x,N0.w}; y2[0]=(v2f){N0.y,N1.x}; z2[0]=(v2f){N0.z,N1.y}; \
            x2[1]=(v2f){N1.z,N2.y}; y2[1]=(v2f){N1.w,N2.z}; z2[1]=(v2f){N2.x,N2.w}; \
            x2[2]=(v2f){N3.x,N3.w}; y2[2]=(v2f){N3.y,N4.x}; z2[2]=(v2f){N3.z,N4.y}; \
            x2[3]=(v2f){N4.z,N5.y}; y2[3]=(v2f){N4.w,N5.z}; z2[3]=(v2f){N5.x,N5.w}; \
        }                                                                      \
        /* prefetch distance 2 into the just-freed buffer */                   \
        {                                                                      \
            const int tp_ = (TCUR) + 2 * NQ;                                   \
            const int pp_ = tp_ * TILESZ + laneOff;                            \
            if (tp_ < ntiles && pp_ + PPL <= L) {                              \
                const float4* __restrict__ m4_ =                               \
                    (const float4*)(mesh + (size_t)pp_ * 3);                   \
                N0 = m4_[0]; N1 = m4_[1]; N2 = m4_[2];                         \
                N3 = m4_[3]; N4 = m4_[4]; N5 = m4_[5];                         \
            }                                                                  \
        }                                                                      \
        if (full_) {                                                           \
            _Pragma("unroll")                                                  \
            for (int j = 0; j < 4; ++j)   /* pk mul/add, no FMA */             \
                ms2[j] = (x2[j] * x2[j] + y2[j] * y2[j]) + z2[j] * z2[j];      \
            if (writer) {                                                      \
                float4* __restrict__ o4 = (float4*)(out + (size_t)p0_ * 4);    \
                o4[0] = make_float4(x2[0].x, y2[0].x, z2[0].x, 0.f);           \
                o4[1] = make_float4(x2[0].y, y2[0].y, z2[0].y, 0.f);           \
                o4[2] = make_float4(x2[1].x, y2[1].x, z2[1].x, 0.f);           \
                o4[3] = make_float4(x2[1].y, y2[1].y, z2[1].y, 0.f);           \
                o4[4] = make_float4(x2[2].x, y2[2].x, z2[2].x, 0.f);           \
                o4[5] = make_float4(x2[2].y, y2[2].y, z2[2].y, 0.f);           \
                o4[6] = make_float4(x2[3].x, y2[3].x, z2[3].x, 0.f);           \
                o4[7] = make_float4(x2[3].y, y2[3].y, z2[3].y, 0.f);           \
            }                                                                  \
        } else {       /* partial tile: scalar path (cold) */                  \
            float xx[PPL], yy[PPL], zz[PPL], mm[PPL];                          \
            _Pragma("unroll")                                                  \
            for (int j = 0; j < PPL; ++j) {                                    \
                const int p = p0_ + j;                                         \
                if (p < L) {                                                   \
                    xx[j] = mesh[(size_t)p * 3 + 0];                           \
                    yy[j] = mesh[(size_t)p * 3 + 1];                           \
                    zz[j] = mesh[(size_t)p * 3 + 2];                           \
                    mm[j] = (xx[j] * xx[j] + yy[j] * yy[j]) + zz[j] * zz[j];   \
                    if (writer) {                                              \
                        out[(size_t)p * 4 + 0] = xx[j];                        \
                        out[(size_t)p * 4 + 1] = yy[j];                        \
                        out[(size_t)p * 4 + 2] = zz[j];                        \
                        out[(size_t)p * 4 + 3] = 0.f;                          \
                    }                                                          \
                } else {                                                       \
                    xx[j] = 0.f; yy[j] = 0.f; zz[j] = 0.f;                     \
                    mm[j] = INFINITY;   /* never selected */                   \
                }                                                              \
            }                                                                  \
            _Pragma("unroll")                                                  \
            for (int j = 0; j < 4; ++j) {                                      \
                x2[j]  = (v2f){xx[2*j], xx[2*j+1]};                            \
                y2[j]  = (v2f){yy[2*j], yy[2*j+1]};                            \
                z2[j]  = (v2f){zz[2*j], zz[2*j+1]};                            \
                ms2[j] = (v2f){mm[2*j], mm[2*j+1]};                            \
            }                                                                  \
        }                                                                      \
        const uint32_t g_ = (uint32_t)(p0_ >> 3);                              \
        _Pragma("unroll")                                                      \
        for (int c = 0; c < RPW; ++c) {                                        \
            v2f vA = pkfma(sp(-2.0f),                                          \
                pkfma(sp(rz[c]), z2[0], pkfma(sp(ry[c]), y2[0], sp(rx[c]) * x2[0])), \
                ms2[0]);                                                       \
            v2f vB = pkfma(sp(-2.0f),                                          \
                pkfma(sp(rz[c]), z2[1], pkfma(sp(ry[c]), y2[1], sp(rx[c]) * x2[1])), \
                ms2[1]);                                                       \
            v2f vC = pkfma(sp(-2.0f),                                          \
                pkfma(sp(rz[c]), z2[2], pkfma(sp(ry[c]), y2[2], sp(rx[c]) * x2[2])), \
                ms2[2]);                                                       \
            v2f vD = pkfma(sp(-2.0f),                                          \
                pkfma(sp(rz[c]), z2[3], pkfma(sp(ry[c]), y2[3], sp(rx[c]) * x2[3])), \
                ms2[3]);                                                       \
            float a_  = fminf(fminf(vA.x, vA.y), vB.x);                        \
            float b_  = fminf(fminf(vB.y, vC.x), vC.y);                        \
            float cc_ = fminf(vD.x, vD.y);                                     \
            float tl_ = fminf(fminf(a_, b_), cc_);                             \
            float d2g = tl_ + rsq[c];   /* == min_j d2_j bit-exact */          \
            if (d2g < best[c]) { best[c] = d2g; grp[c] = g_; }  /* strict < */ \
        }                                                                      \
    }

    // ---- 2x-unrolled steady-state loop (slots A, B alternate) ----
    int t = q0;
    while (t < ntiles) {
        TILE_BODY(A0, A1, A2, A3, A4, A5, t)
        t += NQ;
        if (t >= ntiles) break;
        TILE_BODY(B0, B1, B2, B3, B4, B5, t)
        t += NQ;
    }
#undef TILE_BODY

    // ---- per-wave butterfly reduce on packed (key|group), tiny LDS fold ----
#pragma unroll
    for (int c = 0; c < RPW; ++c) {
        unsigned long long kk =
            ((unsigned long long)monotone_key(best[c]) << 32) | grp[c];
#pragma unroll
        for (int off = 32; off >= 1; off >>= 1) {
            unsigned long long o = shfl_xor_u64(kk, off);
            if (o < kk) kk = o;
        }
        if (lane == 0) wmin[wave][c] = kk;
    }
    __syncthreads();
    if (tid < RPW) {
        unsigned long long kk = wmin[0][tid];
#pragma unroll
        for (int w = 1; w < 4; ++w) {
            unsigned long long o = wmin[w][tid];
            if (o < kk) kk = o;
        }
        const int r = rq * RPW + tid;
        if (r < B) atomicMin(&ws[r], kk);
    }
}

// Recover exact argmin within the winning 8-point group (bit-identical
// re-evaluation, same TU => same contract-off arithmetic), then scatter
// one-hot 1.0 and emit closest_points.
__global__ void finalize_kernel(
        const float* __restrict__ mesh, const float* __restrict__ recv,
        const unsigned long long* __restrict__ ws,
        float* __restrict__ out, int L, int B) {
    const int r = threadIdx.x;
    if (r >= B) return;
    const unsigned long long key = ws[r];
    const int p0 = (int)(key & 0xFFFFFFFFull) << 3;

    const float rx = recv[r * 3 + 0];
    const float ry = recv[r * 3 + 1];
    const float rz = recv[r * 3 + 2];
    const float rsq = (rx * rx + ry * ry) + rz * rz;   // no FMA (pragma)

    float bestd = FLT_MAX;
    int   bidx  = p0;
    for (int j = 0; j < 8; ++j) {
        const int p = p0 + j;
        float d2;
        if (p < L) {
            const float x = mesh[(size_t)p * 3 + 0];
            const float y = mesh[(size_t)p * 3 + 1];
            const float z = mesh[(size_t)p * 3 + 2];
            const float ms = (x * x + y * y) + z * z;
            const float cr = fmaf(rz, z, fmaf(ry, y, rx * x));
            d2 = fmaf(-2.0f, cr, ms) + rsq;
        } else {
            d2 = INFINITY;
        }
        if (d2 < bestd) { bestd = d2; bidx = p; }   // strict <: first index
    }

    out[(size_t)bidx * 4 + 3] = 1.0f;
    float* cp = out + (size_t)L * 4 + (size_t)r * 3;
    cp[0] = mesh[(size_t)bidx * 3 + 0];
    cp[1] = mesh[(size_t)bidx * 3 + 1];
    cp[2] = mesh[(size_t)bidx * 3 + 2];
}

extern "C" void kernel_launch(void* const* d_in, const int* in_sizes, int n_in,
                              void* d_out, int out_size, void* d_ws, size_t ws_size,
                              hipStream_t stream) {
    const float* mesh = (const float*)d_in[0];
    const float* recv = (const float*)d_in[1];
    float* out = (float*)d_out;
    const int L = in_sizes[0] / 3;
    const int B = in_sizes[1] / 3;   // 64
    unsigned long long* ws = (unsigned long long*)d_ws;

    // init per-receiver packed (key|group) mins to all-ones (max)
    hipMemsetAsync(ws, 0xFF, (size_t)B * sizeof(unsigned long long), stream);

    const int ntiles = (L + TILESZ - 1) / TILESZ;
    fused_kernel<<<4 * NQ, 256, 0, stream>>>(mesh, recv, out, ws, L, B, ntiles);

    finalize_kernel<<<1, 64, 0, stream>>>(mesh, recv, ws, out, L, B);
}

// Round 13
// 65.179 us; speedup vs baseline: 3.8041x; 3.8041x over previous
//
#include <hip/hip_runtime.h>
#include <cfloat>
#include <math.h>
#include <stdint.h>

// Match XLA-CPU f32 arithmetic exactly: no implicit contraction anywhere;
// FMA only where written explicitly (Eigen-gemm-style cross product).
// v_pk_fma_f32 / v_pk_mul_f32 / v_pk_add_f32 are IEEE-identical per
// component to their scalar forms, so packing does not change results.
#pragma clang fp contract(off)

typedef float v2f __attribute__((ext_vector_type(2)));

#define RPW 16       // receivers per block (quarter of B=64)
#define NQ  256      // tile phases; grid = 4*NQ = 1024. PROVEN geometry (r3/
                     // r8/r10): co-resident blocks share one tile stream,
                     // FETCH ~30MB (24KB tile fits L1). r5/r6/r11: every
                     // stream-multiplying variant broke locality. DO NOT
                     // change grid layout; this round adds WAVES per block.
#define WAVES 8      // 512-thread blocks: 2x waves/CU at identical geometry
#define PPL 4        // points per lane per tile iteration (512 thr x 4 = 2048)
#define TILESZ 2048  // points per tile (unchanged -> same streams as r10)

__device__ __forceinline__ uint32_t monotone_key(float f) {
    uint32_t u = __float_as_uint(f);
    return (u & 0x80000000u) ? ~u : (u | 0x80000000u);
}

// force a wave-uniform float into an SGPR
__device__ __forceinline__ float rfl_f(float x) {
    return __uint_as_float((uint32_t)__builtin_amdgcn_readfirstlane((int)__float_as_uint(x)));
}

__device__ __forceinline__ unsigned long long shfl_xor_u64(unsigned long long v, int m) {
    uint32_t lo = (uint32_t)v, hi = (uint32_t)(v >> 32);
    lo = (uint32_t)__shfl_xor((int)lo, m, 64);
    hi = (uint32_t)__shfl_xor((int)hi, m, 64);
    return ((unsigned long long)hi << 32) | lo;
}

__device__ __forceinline__ v2f sp(float s) { return (v2f){s, s}; }
__device__ __forceinline__ v2f pkfma(v2f a, v2f b, v2f c) {
    return __builtin_elementwise_fma(a, b, c);   // -> v_pk_fma_f32
}

// lane = 4-point group; 16 receivers in SGPRs; packed-f32 inner loop with
// distance-1 register prefetch (r10 structure; distance-2 spilled in r12:
// VGPR>128 -> scratch, WRITE 765MB. NEVER hold two tile buffers).
// Writer ROTATION ((k+rq)&3)==0: every tile written exactly once, store
// work balanced across the 4 co-walking quarters (kills the rq==0
// straggler). k-based, not t-based: t%4 is constant per block (NQ%4==0).
// Exactness: per-component pk ops == scalar ops; rsq hoist is bit-exact
// (round() monotone => min_j round(v_j+r) == round(min_j v_j + r)); group
// update strict-< in d2-space; packed u64 (mono(d2)<<32 | group) atomicMin
// resolves ties toward the lowest group id => reference first-occurrence
// argmin lies in the winning group; finalize re-evaluates it bit-identically.
// launch_bounds(512,4): cap 128 VGPRs — do NOT squeeze the allocator (r4).
// Natural usage ~55-64 VGPR -> 8 waves/SIMD -> up to 32 waves/CU.
__global__ void __launch_bounds__(512, 4) fused_kernel(
        const float* __restrict__ mesh, const float* __restrict__ recv,
        float* __restrict__ out, unsigned long long* __restrict__ ws,
        int L, int B, int ntiles) {
    __shared__ unsigned long long wmin[WAVES][RPW];

    const int tid  = threadIdx.x;
    const int lane = tid & 63;
    const int wave = tid >> 6;             // 0..7
    const int rq   = blockIdx.x >> 8;      // receiver quarter 0..3
    const int q0   = blockIdx.x & 255;     // tile phase (shared by CU-mates)

    // ---- receiver set into SGPRs (once) ----
    float rx[RPW], ry[RPW], rz[RPW], rsq[RPW];
#pragma unroll
    for (int c = 0; c < RPW; ++c) {
        const int r = rq * RPW + c;
        float x = 0.f, y = 0.f, z = 0.f;
        if (r < B) {                       // uniform branch
            x = recv[r * 3 + 0];
            y = recv[r * 3 + 1];
            z = recv[r * 3 + 2];
        }
        rx[c]  = rfl_f(x);
        ry[c]  = rfl_f(y);
        rz[c]  = rfl_f(z);
        rsq[c] = rfl_f((x * x + y * y) + z * z);   // no FMA (pragma)
    }

    float    best[RPW];
    uint32_t grp[RPW];
#pragma unroll
    for (int c = 0; c < RPW; ++c) { best[c] = FLT_MAX; grp[c] = 0; }

    const int laneOff = (wave << 8) + (lane << 2);   // 4 pts per lane

    // ---- distance-1 prologue: load first tile's 3 float4 ----
    float4 nb0, nb1, nb2;
    int  t  = q0;
    int  k  = 0;                           // tile-iteration counter
    int  p0 = t * TILESZ + laneOff;
    bool curFull = (t < ntiles) && (p0 + PPL <= L);
    if (curFull) {
        const float4* __restrict__ m4 = (const float4*)(mesh + (size_t)p0 * 3);
        nb0 = m4[0]; nb1 = m4[1]; nb2 = m4[2];
    }

    while (t < ntiles) {
        const bool writer = (((k + rq) & 3) == 0);   // balanced rotation
        v2f x2[2], y2[2], z2[2], ms2[2];
        if (curFull) {
            // consume prefetch buffer: pack point-pairs (0,1) and (2,3)
            x2[0] = (v2f){nb0.x, nb0.w}; y2[0] = (v2f){nb0.y, nb1.x}; z2[0] = (v2f){nb0.z, nb1.y};
            x2[1] = (v2f){nb1.z, nb2.y}; y2[1] = (v2f){nb1.w, nb2.z}; z2[1] = (v2f){nb2.x, nb2.w};
        }

        // ---- prefetch next tile (nb dead now); eval hides the latency ----
        const int  tn  = t + NQ;
        const int  pn0 = tn * TILESZ + laneOff;
        const bool nextFull = (tn < ntiles) && (pn0 + PPL <= L);
        if (nextFull) {
            const float4* __restrict__ m4 = (const float4*)(mesh + (size_t)pn0 * 3);
            nb0 = m4[0]; nb1 = m4[1]; nb2 = m4[2];
        }

        if (curFull) {
#pragma unroll
            for (int j = 0; j < 2; ++j)
                ms2[j] = (x2[j] * x2[j] + y2[j] * y2[j]) + z2[j] * z2[j];  // pk, no FMA
            if (writer) {
                float4* __restrict__ o4 = (float4*)(out + (size_t)p0 * 4);
                o4[0] = make_float4(x2[0].x, y2[0].x, z2[0].x, 0.f);
                o4[1] = make_float4(x2[0].y, y2[0].y, z2[0].y, 0.f);
                o4[2] = make_float4(x2[1].x, y2[1].x, z2[1].x, 0.f);
                o4[3] = make_float4(x2[1].y, y2[1].y, z2[1].y, 0.f);
            }
        } else {
            float xx[PPL], yy[PPL], zz[PPL], mm[PPL];
#pragma unroll
            for (int j = 0; j < PPL; ++j) {
                const int p = p0 + j;
                if (p < L) {
                    xx[j] = mesh[(size_t)p * 3 + 0];
                    yy[j] = mesh[(size_t)p * 3 + 1];
                    zz[j] = mesh[(size_t)p * 3 + 2];
                    mm[j] = (xx[j] * xx[j] + yy[j] * yy[j]) + zz[j] * zz[j];
                    if (writer) {
                        out[(size_t)p * 4 + 0] = xx[j];
                        out[(size_t)p * 4 + 1] = yy[j];
                        out[(size_t)p * 4 + 2] = zz[j];
                        out[(size_t)p * 4 + 3] = 0.f;
                    }
                } else {
                    xx[j] = 0.f; yy[j] = 0.f; zz[j] = 0.f;
                    mm[j] = INFINITY;      // v = +inf, never selected
                }
            }
#pragma unroll
            for (int j = 0; j < 2; ++j) {
                x2[j]  = (v2f){xx[2 * j], xx[2 * j + 1]};
                y2[j]  = (v2f){yy[2 * j], yy[2 * j + 1]};
                z2[j]  = (v2f){zz[2 * j], zz[2 * j + 1]};
                ms2[j] = (v2f){mm[2 * j], mm[2 * j + 1]};
            }
        }

        // ---- packed eval: 4 points x 16 receivers ----
        const uint32_t g = (uint32_t)(p0 >> 2);   // 4-point group id
#pragma unroll
        for (int c = 0; c < RPW; ++c) {
            v2f vA = pkfma(sp(-2.0f),
                           pkfma(sp(rz[c]), z2[0], pkfma(sp(ry[c]), y2[0], sp(rx[c]) * x2[0])),
                           ms2[0]);
            v2f vB = pkfma(sp(-2.0f),
                           pkfma(sp(rz[c]), z2[1], pkfma(sp(ry[c]), y2[1], sp(rx[c]) * x2[1])),
                           ms2[1]);
            // min-tree over 4 components (exact: min assoc/comm)
            float tl = fminf(fminf(vA.x, vA.y), fminf(vB.x, vB.y));
            float d2g = tl + rsq[c];       // == min_j d2_j bit-exact (monotone)
            if (d2g < best[c]) { best[c] = d2g; grp[c] = g; }   // strict <
        }

        t = tn; p0 = pn0; curFull = nextFull; ++k;
    }

    // ---- per-wave butterfly reduce on packed (key|group), tiny LDS fold ----
#pragma unroll
    for (int c = 0; c < RPW; ++c) {
        unsigned long long kk =
            ((unsigned long long)monotone_key(best[c]) << 32) | grp[c];
#pragma unroll
        for (int off = 32; off >= 1; off >>= 1) {
            unsigned long long o = shfl_xor_u64(kk, off);
            if (o < kk) kk = o;
        }
        if (lane == 0) wmin[wave][c] = kk;
    }
    __syncthreads();
    if (tid < RPW) {
        unsigned long long kk = wmin[0][tid];
#pragma unroll
        for (int w = 1; w < WAVES; ++w) {
            unsigned long long o = wmin[w][tid];
            if (o < kk) kk = o;
        }
        const int r = rq * RPW + tid;
        if (r < B) atomicMin(&ws[r], kk);
    }
}

// Recover exact argmin within the winning 4-point group (bit-identical
// re-evaluation, same TU => same contract-off arithmetic), then scatter
// one-hot 1.0 and emit closest_points.
__global__ void finalize_kernel(
        const float* __restrict__ mesh, const float* __restrict__ recv,
        const unsigned long long* __restrict__ ws,
        float* __restrict__ out, int L, int B) {
    const int r = threadIdx.x;
    if (r >= B) return;
    const unsigned long long key = ws[r];
    const int p0 = (int)(key & 0xFFFFFFFFull) << 2;

    const float rx = recv[r * 3 + 0];
    const float ry = recv[r * 3 + 1];
    const float rz = recv[r * 3 + 2];
    const float rsq = (rx * rx + ry * ry) + rz * rz;   // no FMA (pragma)

    float bestd = FLT_MAX;
    int   bidx  = p0;
    for (int j = 0; j < PPL; ++j) {
        const int p = p0 + j;
        float d2;
        if (p < L) {
            const float x = mesh[(size_t)p * 3 + 0];
            const float y = mesh[(size_t)p * 3 + 1];
            const float z = mesh[(size_t)p * 3 + 2];
            const float ms = (x * x + y * y) + z * z;
            const float cr = fmaf(rz, z, fmaf(ry, y, rx * x));
            d2 = fmaf(-2.0f, cr, ms) + rsq;
        } else {
            d2 = INFINITY;
        }
        if (d2 < bestd) { bestd = d2; bidx = p; }   // strict <: first index
    }

    out[(size_t)bidx * 4 + 3] = 1.0f;
    float* cp = out + (size_t)L * 4 + (size_t)r * 3;
    cp[0] = mesh[(size_t)bidx * 3 + 0];
    cp[1] = mesh[(size_t)bidx * 3 + 1];
    cp[2] = mesh[(size_t)bidx * 3 + 2];
}

extern "C" void kernel_launch(void* const* d_in, const int* in_sizes, int n_in,
                              void* d_out, int out_size, void* d_ws, size_t ws_size,
                              hipStream_t stream) {
    const float* mesh = (const float*)d_in[0];
    const float* recv = (const float*)d_in[1];
    float* out = (float*)d_out;
    const int L = in_sizes[0] / 3;
    const int B = in_sizes[1] / 3;   // 64
    unsigned long long* ws = (unsigned long long*)d_ws;

    // init per-receiver packed (key|group) mins to all-ones (max)
    hipMemsetAsync(ws, 0xFF, (size_t)B * sizeof(unsigned long long), stream);

    const int ntiles = (L + TILESZ - 1) / TILESZ;
    fused_kernel<<<4 * NQ, 512, 0, stream>>>(mesh, recv, out, ws, L, B, ntiles);

    finalize_kernel<<<1, 64, 0, stream>>>(mesh, recv, ws, out, L, B);
}